// Round 1
// baseline (8117.561 us; speedup 1.0000x reference)
//
#include <hip/hip_runtime.h>
#include <math.h>

// L=1024, B=24, D=512.
// Pipeline: tk=tanh(v.Wp_^T) [full]; per 128-i chunk: tq, fused
// scores+softmax+context (attn), Gi = C.w_ih^T+b_ih, then a persistent GRU
// kernel doing 128 steps with tagged-word handshakes.
// R4 lesson: launch_bounds(512,2) gave 128 regs/lane -> 192-float wreg spilled.
// R5 (this round): GRU was latency-bound (3.63us/step, VALUBusy 14%).
//  - flags removed: h published as {float,tag} 8B relaxed agent atomics;
//    consumers poll the data words directly (one store one-way + one poll RT
//    instead of release-drain + flag hop + separate h load).
//  - 64 blocks (8 slices x 8 groups); each block time-multiplexes 3 batches
//    with the SAME register-resident w_hh slice -> publish->need gap of one
//    batch is filled by the other two chains (latency hidden).
//  - 2 barriers/step (was 4); old-h carried in a register; out store after
//    publish; exp/rcp-based gates instead of libm tanhf / fdiv.

// ---------------------------------------------------------------------------
// GEMM: out[m][n] = post(A[m][:] . B[n][:] (+ bias[n])), A: MxK rm, B: NxK rm.
__launch_bounds__(256, 2)
__global__ void gemm_abt_kernel(const float* __restrict__ A, const float* __restrict__ B,
                                float* __restrict__ out, int K, int N,
                                const float* __restrict__ bias, int do_tanh) {
  __shared__ __align__(16) float As[16][136];
  __shared__ __align__(16) float Bs[16][136];
  const int m0 = blockIdx.y * 128, n0 = blockIdx.x * 128;
  const int tid = threadIdx.x;
  const int tm = (tid & 15) * 8, tn = (tid >> 4) * 8;
  const int srow = tid & 127, scol = (tid >> 7) * 8;
  const float* Ap = A + (size_t)(m0 + srow) * K + scol;
  const float* Bp = B + (size_t)(n0 + srow) * K + scol;
  float acc[8][8] = {{0.f}};
  for (int k0 = 0; k0 < K; k0 += 16) {
    const float4 a0 = *(const float4*)(Ap + k0);
    const float4 a1 = *(const float4*)(Ap + k0 + 4);
    const float4 b0 = *(const float4*)(Bp + k0);
    const float4 b1 = *(const float4*)(Bp + k0 + 4);
    __syncthreads();
    As[scol + 0][srow] = a0.x; As[scol + 1][srow] = a0.y;
    As[scol + 2][srow] = a0.z; As[scol + 3][srow] = a0.w;
    As[scol + 4][srow] = a1.x; As[scol + 5][srow] = a1.y;
    As[scol + 6][srow] = a1.z; As[scol + 7][srow] = a1.w;
    Bs[scol + 0][srow] = b0.x; Bs[scol + 1][srow] = b0.y;
    Bs[scol + 2][srow] = b0.z; Bs[scol + 3][srow] = b0.w;
    Bs[scol + 4][srow] = b1.x; Bs[scol + 5][srow] = b1.y;
    Bs[scol + 6][srow] = b1.z; Bs[scol + 7][srow] = b1.w;
    __syncthreads();
#pragma unroll
    for (int kk = 0; kk < 16; ++kk) {
      const float4 av0 = *(const float4*)&As[kk][tm];
      const float4 av1 = *(const float4*)&As[kk][tm + 4];
      const float4 bv0 = *(const float4*)&Bs[kk][tn];
      const float4 bv1 = *(const float4*)&Bs[kk][tn + 4];
      const float ar[8] = {av0.x, av0.y, av0.z, av0.w, av1.x, av1.y, av1.z, av1.w};
      const float br[8] = {bv0.x, bv0.y, bv0.z, bv0.w, bv1.x, bv1.y, bv1.z, bv1.w};
#pragma unroll
      for (int r = 0; r < 8; ++r)
#pragma unroll
        for (int c = 0; c < 8; ++c)
          acc[r][c] = fmaf(ar[r], br[c], acc[r][c]);
    }
  }
#pragma unroll
  for (int r = 0; r < 8; ++r) {
    float* o = out + (size_t)(m0 + tm + r) * N + n0 + tn;
#pragma unroll
    for (int c = 0; c < 8; ++c) {
      float val = acc[r][c];
      if (bias) val += bias[n0 + tn + c];
      if (do_tanh) val = tanhf(val);
      o[c] = val;
    }
  }
}

// ---------------------------------------------------------------------------
// Fused scores + softmax + context for one i-chunk.
// tanh(q+k) = u + w(1-u^2)/(1+uw); sum_h V*u is const in l -> dropped
// (softmax-invariant). V'[i][h] = V[h]*(1-u^2) lives in registers.
__launch_bounds__(256, 3)
__global__ void attn_kernel(const float* __restrict__ tq, const float* __restrict__ tk,
                            const float* __restrict__ Vv, const float* __restrict__ v,
                            float* __restrict__ Cout) {
  const int b = blockIdx.y;
  const int it = blockIdx.x;           // i-tile within chunk (il = it*4+ii)
  const int tid = threadIdx.x;
  const int wave = tid >> 6, lane = tid & 63;
  const int h8 = lane * 8;
  __shared__ __align__(16) float sm[4][1024];
  __shared__ __align__(16) float red[4][4][512];
  __shared__ float inv_s[4];

  float q[4][8], vp[4][8];
  {
    const float* vvp = Vv + (size_t)b * 512 + h8;
    const float4 v0 = *(const float4*)vvp;
    const float4 v1 = *(const float4*)(vvp + 4);
    const float vv[8] = {v0.x, v0.y, v0.z, v0.w, v1.x, v1.y, v1.z, v1.w};
#pragma unroll
    for (int ii = 0; ii < 4; ++ii) {
      const float* qp = tq + ((size_t)(it * 4 + ii) * 24 + b) * 512 + h8;
      const float4 q0 = *(const float4*)qp;
      const float4 q1 = *(const float4*)(qp + 4);
      q[ii][0] = q0.x; q[ii][1] = q0.y; q[ii][2] = q0.z; q[ii][3] = q0.w;
      q[ii][4] = q1.x; q[ii][5] = q1.y; q[ii][6] = q1.z; q[ii][7] = q1.w;
#pragma unroll
      for (int j = 0; j < 8; ++j)
        vp[ii][j] = vv[j] * (1.0f - q[ii][j] * q[ii][j]);
    }
  }

  for (int l = wave; l < 1024; l += 4) {
    const float* kp = tk + ((size_t)l * 24 + b) * 512 + h8;
    const float4 k0 = *(const float4*)kp;
    const float4 k1 = *(const float4*)(kp + 4);
    const float kkv[8] = {k0.x, k0.y, k0.z, k0.w, k1.x, k1.y, k1.z, k1.w};
    float acc0 = 0.f, acc1 = 0.f, acc2 = 0.f, acc3 = 0.f;
#pragma unroll
    for (int j = 0; j < 8; ++j) {
      const float w = kkv[j];
      acc0 = fmaf(vp[0][j] * w, __builtin_amdgcn_rcpf(fmaf(q[0][j], w, 1.0f)), acc0);
      acc1 = fmaf(vp[1][j] * w, __builtin_amdgcn_rcpf(fmaf(q[1][j], w, 1.0f)), acc1);
      acc2 = fmaf(vp[2][j] * w, __builtin_amdgcn_rcpf(fmaf(q[2][j], w, 1.0f)), acc2);
      acc3 = fmaf(vp[3][j] * w, __builtin_amdgcn_rcpf(fmaf(q[3][j], w, 1.0f)), acc3);
    }
#pragma unroll
    for (int mask = 32; mask; mask >>= 1) {
      acc0 += __shfl_xor(acc0, mask, 64);
      acc1 += __shfl_xor(acc1, mask, 64);
      acc2 += __shfl_xor(acc2, mask, 64);
      acc3 += __shfl_xor(acc3, mask, 64);
    }
    if (lane == 0) {
      sm[0][l] = acc0; sm[1][l] = acc1; sm[2][l] = acc2; sm[3][l] = acc3;
    }
  }
  __syncthreads();

  // softmax of row `wave` in place (exp only; normalization folded into output)
  {
    float* row = sm[wave];
    float m = -1e30f;
    for (int t = lane; t < 1024; t += 64) m = fmaxf(m, row[t]);
#pragma unroll
    for (int mask = 32; mask; mask >>= 1) m = fmaxf(m, __shfl_xor(m, mask, 64));
    float s = 0.f;
    for (int t = lane; t < 1024; t += 64) {
      const float e = __expf(row[t] - m);
      row[t] = e;
      s += e;
    }
#pragma unroll
    for (int mask = 32; mask; mask >>= 1) s += __shfl_xor(s, mask, 64);
    if (lane == 0) inv_s[wave] = 1.0f / s;
  }
  __syncthreads();

  // context: wave w covers l in [256w, 256w+256), lane owns d-slice h8
  float ca[4][8] = {{0.f}};
  const int l0 = wave * 256;
  for (int l = l0; l < l0 + 256; ++l) {
    const float* vrow = v + ((size_t)l * 24 + b) * 512 + h8;
    const float4 x0 = *(const float4*)vrow;
    const float4 x1 = *(const float4*)(vrow + 4);
    const float a0 = sm[0][l], a1 = sm[1][l], a2 = sm[2][l], a3 = sm[3][l];
    const float xv[8] = {x0.x, x0.y, x0.z, x0.w, x1.x, x1.y, x1.z, x1.w};
#pragma unroll
    for (int j = 0; j < 8; ++j) {
      ca[0][j] = fmaf(a0, xv[j], ca[0][j]);
      ca[1][j] = fmaf(a1, xv[j], ca[1][j]);
      ca[2][j] = fmaf(a2, xv[j], ca[2][j]);
      ca[3][j] = fmaf(a3, xv[j], ca[3][j]);
    }
  }
#pragma unroll
  for (int ii = 0; ii < 4; ++ii) {
    *(float4*)&red[wave][ii][h8]     = make_float4(ca[ii][0], ca[ii][1], ca[ii][2], ca[ii][3]);
    *(float4*)&red[wave][ii][h8 + 4] = make_float4(ca[ii][4], ca[ii][5], ca[ii][6], ca[ii][7]);
  }
  __syncthreads();
  {
    const int ii = tid >> 6;
    const int d0 = (tid & 63) * 8;
    float4 s0 = *(const float4*)&red[0][ii][d0];
    float4 s1 = *(const float4*)&red[0][ii][d0 + 4];
#pragma unroll
    for (int w = 1; w < 4; ++w) {
      const float4 r0 = *(const float4*)&red[w][ii][d0];
      const float4 r1 = *(const float4*)&red[w][ii][d0 + 4];
      s0.x += r0.x; s0.y += r0.y; s0.z += r0.z; s0.w += r0.w;
      s1.x += r1.x; s1.y += r1.y; s1.z += r1.z; s1.w += r1.w;
    }
    const float inv = inv_s[ii];
    s0.x *= inv; s0.y *= inv; s0.z *= inv; s0.w *= inv;
    s1.x *= inv; s1.y *= inv; s1.z *= inv; s1.w *= inv;
    float* o = Cout + ((size_t)(it * 4 + ii) * 24 + b) * 512 + d0;
    *(float4*)o = s0;
    *(float4*)(o + 4) = s1;
  }
}

// ---------------------------------------------------------------------------
// Persistent GRU with tagged-word handshakes.
// Grid 64 = 8 d-slices x 8 groups; group g owns batches {3g,3g+1,3g+2} and
// time-multiplexes them with one shared register-resident w_hh slice.
// h exchange: {float h; u32 tag} packed in one 8B relaxed agent-scope atomic.
// tag(h_g) = g+1; consumer at step gs polls word tags >= gs+1; producer at
// step gs stores h_{gs+1} with tag gs+2. Ping-pong (hb0/hb1 by parity) makes
// slot overwrite provably ordered after all consumers of the old value.
union HPack {
  unsigned long long u;
  struct { float f; unsigned tag; } s;
};

__launch_bounds__(512, 1)
__global__ void gru_persist_kernel(const float* __restrict__ Gi_c,
                                   const float* __restrict__ w_hh,
                                   const float* __restrict__ b_hh,
                                   const float* __restrict__ h0,
                                   unsigned long long* __restrict__ hb0,
                                   unsigned long long* __restrict__ hb1,
                                   float* __restrict__ out, int gstep0) {
  const int g  = blockIdx.x & 7;    // batch group (idx%8 -> likely same XCD per group)
  const int sl = blockIdx.x >> 3;   // d-slice
  const int t = threadIdx.x;
  const int d_loc = t & 63;
  const int kc = t >> 6;
  const int dglob = sl * 64 + d_loc;

  __shared__ __align__(16) float h_lds[512];
  __shared__ float red[3][64][9];   // stride 9 (odd) -> conflict-free both axes

  // pin weight fragments in registers (192 floats/thread; fits at 1 blk/CU)
  float wreg[3][64];
#pragma unroll
  for (int gg = 0; gg < 3; ++gg) {
    const float* wr = w_hh + (size_t)(gg * 512 + dglob) * 512 + kc * 64;
#pragma unroll
    for (int j = 0; j < 64; j += 4) {
      const float4 wv = *(const float4*)(wr + j);
      wreg[gg][j] = wv.x; wreg[gg][j + 1] = wv.y; wreg[gg][j + 2] = wv.z; wreg[gg][j + 3] = wv.w;
    }
  }
  const float bias_r = b_hh[dglob];
  const float bias_z = b_hh[512 + dglob];
  const float bias_n = b_hh[1024 + dglob];

  // Launch 0: seed h0 into hb1 with tag 1 (memset zeroed all tags first).
  // Consumers self-synchronize by polling, so no fence/barrier needed here.
  if (gstep0 == 0 && t < 192) {
    const int q = t >> 6, d = t & 63;
    const int bg = g * 3 + q;
    HPack p;
    p.s.f = h0[(size_t)bg * 512 + sl * 64 + d];
    p.s.tag = 1u;
    __hip_atomic_store(hb1 + (size_t)bg * 512 + sl * 64 + d, p.u,
                       __ATOMIC_RELAXED, __HIP_MEMORY_SCOPE_AGENT);
  }

  float hq[3];   // own h slice per batch, carried in a register (q fully unrolled)
  HPack pf;      // prefetched tagged word for the upcoming segment
  pf.u = __hip_atomic_load(((gstep0 & 1) ? hb0 : hb1) + (size_t)(g * 3) * 512 + t,
                           __ATOMIC_RELAXED, __HIP_MEMORY_SCOPE_AGENT);

  for (int il = 0; il < 128; ++il) {
    const int gs = gstep0 + il;
#pragma unroll
    for (int q = 0; q < 3; ++q) {
      const int bg = g * 3 + q;
      const unsigned want = (unsigned)(gs + 1);
      const unsigned long long* src = ((gs & 1) ? hb0 : hb1) + (size_t)bg * 512 + t;

      HPack p = pf;
      // issue next segment's prefetch now; its latency hides under the matvec
      {
        const int gs_n = (q == 2) ? gs + 1 : gs;
        const int bg_n = (q == 2) ? g * 3 : bg + 1;
        pf.u = __hip_atomic_load(((gs_n & 1) ? hb0 : hb1) + (size_t)bg_n * 512 + t,
                                 __ATOMIC_RELAXED, __HIP_MEMORY_SCOPE_AGENT);
      }
      // fast path: tag already current (published >=2 segments ago)
      while (p.s.tag < want) {
        __builtin_amdgcn_s_sleep(1);
        p.u = __hip_atomic_load(src, __ATOMIC_RELAXED, __HIP_MEMORY_SCOPE_AGENT);
      }
      h_lds[t] = p.s.f;

      // hoist gi loads (consumed after the reduce)
      float gir = 0.f, giz = 0.f, gin = 0.f;
      if (t < 64) {
        const float* gi = Gi_c + ((size_t)il * 24 + bg) * 1536;
        gir = gi[dglob]; giz = gi[512 + dglob]; gin = gi[1024 + dglob];
      }
      __syncthreads();   // B1: h_lds ready; also orders red WAR vs prev gate reads
      if (il == 0 && t < 64) hq[q] = h_lds[dglob];

      // partial dots over k in [kc*64, kc*64+64); 6 independent FMA chains
      float a0 = 0.f, a1 = 0.f, a2 = 0.f, b0 = 0.f, b1 = 0.f, b2 = 0.f;
#pragma unroll
      for (int j = 0; j < 64; j += 8) {
        const float4 h1 = *(const float4*)&h_lds[kc * 64 + j];
        const float4 h2 = *(const float4*)&h_lds[kc * 64 + j + 4];
        a0 = fmaf(h1.x, wreg[0][j], fmaf(h1.y, wreg[0][j+1], fmaf(h1.z, wreg[0][j+2], fmaf(h1.w, wreg[0][j+3], a0))));
        b0 = fmaf(h2.x, wreg[0][j+4], fmaf(h2.y, wreg[0][j+5], fmaf(h2.z, wreg[0][j+6], fmaf(h2.w, wreg[0][j+7], b0))));
        a1 = fmaf(h1.x, wreg[1][j], fmaf(h1.y, wreg[1][j+1], fmaf(h1.z, wreg[1][j+2], fmaf(h1.w, wreg[1][j+3], a1))));
        b1 = fmaf(h2.x, wreg[1][j+4], fmaf(h2.y, wreg[1][j+5], fmaf(h2.z, wreg[1][j+6], fmaf(h2.w, wreg[1][j+7], b1))));
        a2 = fmaf(h1.x, wreg[2][j], fmaf(h1.y, wreg[2][j+1], fmaf(h1.z, wreg[2][j+2], fmaf(h1.w, wreg[2][j+3], a2))));
        b2 = fmaf(h2.x, wreg[2][j+4], fmaf(h2.y, wreg[2][j+5], fmaf(h2.z, wreg[2][j+6], fmaf(h2.w, wreg[2][j+7], b2))));
      }
      red[0][d_loc][kc] = a0 + b0;
      red[1][d_loc][kc] = a1 + b1;
      red[2][d_loc][kc] = a2 + b2;
      __syncthreads();   // B2: partials ready

      if (t < 64) {
        const float* r0 = red[0][t];
        const float* r1 = red[1][t];
        const float* r2 = red[2][t];
        const float sr = ((r0[0] + r0[1]) + (r0[2] + r0[3])) + ((r0[4] + r0[5]) + (r0[6] + r0[7]));
        const float sz = ((r1[0] + r1[1]) + (r1[2] + r1[3])) + ((r1[4] + r1[5]) + (r1[6] + r1[7]));
        const float sn = ((r2[0] + r2[1]) + (r2[2] + r2[3])) + ((r2[4] + r2[5]) + (r2[6] + r2[7]));
        const float r = __builtin_amdgcn_rcpf(1.0f + __expf(-(gir + sr + bias_r)));
        const float z = __builtin_amdgcn_rcpf(1.0f + __expf(-(giz + sz + bias_z)));
        const float nx = gin + r * (sn + bias_n);
        const float e2 = __expf(-2.0f * fabsf(nx));
        const float tn = __builtin_copysignf((1.0f - e2) * __builtin_amdgcn_rcpf(1.0f + e2), nx);
        const float hn = (1.0f - z) * tn + z * hq[q];
        hq[q] = hn;
        HPack pw; pw.s.f = hn; pw.s.tag = (unsigned)(gs + 2);
        __hip_atomic_store(((gs & 1) ? hb1 : hb0) + (size_t)bg * 512 + dglob, pw.u,
                           __ATOMIC_RELAXED, __HIP_MEMORY_SCOPE_AGENT);
        out[((size_t)gs * 24 + bg) * 512 + dglob] = hn;   // after publish: off chain
      }
      // no trailing barrier: h_lds writers of the next segment are post-B2,
      // all h_lds readers are pre-B2; red WAR is covered by the next B1
      // (wave0 reaches it only after its red reads).
    }
  }
}

// ---------------------------------------------------------------------------
extern "C" void kernel_launch(void* const* d_in, const int* in_sizes, int n_in,
                              void* d_out, int out_size, void* d_ws, size_t ws_size,
                              hipStream_t stream) {
  (void)in_sizes; (void)n_in; (void)out_size;
  const float* v    = (const float*)d_in[0];
  const float* h0   = (const float*)d_in[1];
  const float* Vv   = (const float*)d_in[2];
  const float* Wp   = (const float*)d_in[3];
  const float* Wp_  = (const float*)d_in[4];
  const float* w_ih = (const float*)d_in[5];
  const float* w_hh = (const float*)d_in[6];
  const float* b_ih = (const float*)d_in[7];
  const float* b_hh = (const float*)d_in[8];
  float* out = (float*)d_out;

  // workspace layout; full-tq path needs 126,025,728 B, chunked 81,985,536 B
  const bool full_tq = ws_size >= (size_t)126025728;
  float* ws   = (float*)d_ws;
  float* tk   = ws;                                  // 12,582,912 fl
  float* tqF  = tk + (size_t)12582912;               // full path only
  float* tq_c = tk + (size_t)12582912;               // chunked path only
  float* C_c  = full_tq ? (tqF + (size_t)12582912) : (tq_c + (size_t)1572864);
  float* Gi_c = C_c + (size_t)1572864;               // 4,718,592 fl
  unsigned long long* hb0 = (unsigned long long*)(Gi_c + (size_t)4718592); // 24*512 u64
  unsigned long long* hb1 = hb0 + (size_t)12288;                           // 24*512 u64

  // zero the tagged h buffers once per call (tags are monotone across the
  // 8 GRU launches; replays re-zero via the captured memset)
  hipMemsetAsync(hb0, 0, (size_t)2 * 12288 * sizeof(unsigned long long), stream);

  // key projection (full): tk = tanh(v . Wp_^T)
  gemm_abt_kernel<<<dim3(4, 192), 256, 0, stream>>>(v, Wp_, tk, 512, 512, nullptr, 1);
  if (full_tq)
    gemm_abt_kernel<<<dim3(4, 192), 256, 0, stream>>>(v, Wp, tqF, 512, 512, nullptr, 1);

  for (int c = 0; c < 8; ++c) {
    const float* v_chunk = v + (size_t)c * 128 * 24 * 512;
    const float* tq_use;
    if (full_tq) {
      tq_use = tqF + (size_t)c * 128 * 24 * 512;
    } else {
      gemm_abt_kernel<<<dim3(4, 24), 256, 0, stream>>>(v_chunk, Wp, tq_c, 512, 512, nullptr, 1);
      tq_use = tq_c;
    }
    attn_kernel<<<dim3(32, 24), 256, 0, stream>>>(tq_use, tk, Vv, v, C_c);
    gemm_abt_kernel<<<dim3(12, 24), 256, 0, stream>>>(C_c, w_ih, Gi_c, 512, 1536, b_ih, 0);
    gru_persist_kernel<<<64, 512, 0, stream>>>(Gi_c, w_hh, b_hh, h0, hb0, hb1,
                                               out, c * 128);
  }
}